// Round 4
// baseline (205.914 us; speedup 1.0000x reference)
//
#include <hip/hip_runtime.h>
#include <math.h>

#define NEGV -1e30f

constexpr int Bc = 256;          // batch
constexpr int Tc = 256;          // time
constexpr int Cc = 512;          // classes (blank = Cc-1)
constexpr int Lc = 64;           // max label length
constexpr int PW = 8;            // producer waves
constexpr int GR = 16;           // timesteps per phase (2 rows per producer wave)
constexpr int NPH = Tc / GR;     // 16 phases
constexpr float INVLN2 = 1.44269504088896340736f;
constexpr float LN2    = 0.69314718055994530942f;

// log2-domain logaddexp: log2(2^a + 2^b). Exact; NEGV-safe.
__device__ __forceinline__ float la2(float a, float b) {
    float m = fmaxf(a, b);
    float d = fabsf(a - b);
    return m + __log2f(exp2f(-d) + 1.0f);
}

// 3-way log2-sum-exp: log2(2^a + 2^b + 2^c). One log2 on the critical path.
__device__ __forceinline__ float lse3(float a, float b, float c) {
    float m = fmaxf(fmaxf(a, b), c);         // clang fuses to v_max3_f32
    return m + __log2f(exp2f(a - m) + exp2f(b - m) + exp2f(c - m));
}

// lane l gets x from lane l-1; lane 0 gets `fill`. DPP wave_shr:1 — pure VALU.
__device__ __forceinline__ float dpp_shr1(float x, float fill) {
    int r = __builtin_amdgcn_update_dpp(__float_as_int(fill), __float_as_int(x),
                                        0x138 /*wave_shr:1*/, 0xF, 0xF, false);
    return __int_as_float(r);
}

// Wave64 sum-reduce entirely on the VALU via DPP (~45 cy dependent latency,
// no ds_bpermute round-trips). Result broadcast from lane 63 via readlane.
__device__ __forceinline__ float wave_sum_dpp(float v) {
#define DPPADD(ctrl)                                                          \
    v += __int_as_float(__builtin_amdgcn_update_dpp(                          \
        0, __float_as_int(v), (ctrl), 0xF, 0xF, true))
    DPPADD(0x111);   // row_shr:1
    DPPADD(0x112);   // row_shr:2
    DPPADD(0x114);   // row_shr:4
    DPPADD(0x118);   // row_shr:8
    DPPADD(0x142);   // row_bcast:15
    DPPADD(0x143);   // row_bcast:31
#undef DPPADD
    return __int_as_float(__builtin_amdgcn_readlane(__float_as_int(v), 63));
}

// Barrier WITHOUT the vmcnt(0) drain __syncthreads would emit: LDS writes must
// be visible (lgkmcnt(0)) but prefetched global loads stay in flight across
// phases. sched_barrier(0) fences guard against compiler hoisting (rule #18).
__device__ __forceinline__ void phase_barrier() {
    __builtin_amdgcn_sched_barrier(0);
    asm volatile("s_waitcnt lgkmcnt(0)" ::: "memory");
    __builtin_amdgcn_sched_barrier(0);
    __builtin_amdgcn_s_barrier();
    __builtin_amdgcn_sched_barrier(0);
}

// ---------------------------------------------------------------------------
// Fused CTC: one block (9 waves, 576 thr) per batch, barrier-phased.
// Round-4 change vs round 3: 16 phases x 16 timesteps (was 32 x 8). Producer
// wave w handles rows t0+w and t0+8+w per phase. This doubles the
// prefetch lead time (~3200 cy >> HBM latency ~900-2000 cy loaded) so the
// per-phase vmcnt stall disappears, and halves the 9-wave barrier count.
// Phase p: producers compute group p from registers prefetched in phase p-1
// (coalesced float4 pairs for the lse + per-lane global gather of
// logits[b,t,y_lane]); DPP sum-reduce; write 65 emission floats per row into
// slot p&1 of a 2-slot LDS ring. Wave 8 consumes group p-1 from slot (p-1)&1:
// 16 recurrence steps (lse3 on the skip path). One lgkmcnt-only barrier per
// phase.
// ---------------------------------------------------------------------------
__global__ __launch_bounds__(576) void ctc_k(const float* __restrict__ logits,
                                             const int* __restrict__ labels,
                                             const int* __restrict__ lab_len,
                                             const int* __restrict__ log_len,
                                             float* __restrict__ nll) {
    const int b    = blockIdx.x;
    const int tid  = threadIdx.x;
    const int w    = tid >> 6;               // wave id 0..8
    const int lane = tid & 63;

    __shared__ float em[2][GR][66];          // 8.4 KB: [slot][row][lane|64=blank]

    const float* base = logits + (size_t)b * Tc * Cc;
    const int y = labels[b * Lc + lane];     // label of this lane (all waves)

    // ---- producer registers: rows {w, w+8} of group 0 ----
    float4 cA0, cA1, cB0, cB1; float cgA, cgB;
    if (w < PW) {
        const float4* pA = (const float4*)(base + (size_t)w * Cc);
        const float4* pB = (const float4*)(base + (size_t)(w + 8) * Cc);
        cA0 = pA[lane]; cA1 = pA[lane + 64];
        cB0 = pB[lane]; cB1 = pB[lane + 64];
        cgA = base[(size_t)w * Cc + y];          // per-lane gather (L1-hot)
        cgB = base[(size_t)(w + 8) * Cc + y];
    }

    // ---- consumer state (wave 8) ----
    const int  prevlab = __shfl_up(y, 1, 64);
    const bool skip    = (lane >= 1) && (y != prevlab);
    const int  llm1    = log_len[b] - 1;
    float ae = NEGV, ao = NEGV, ax = NEGV;   // alpha2[2l], alpha2[2l+1], alpha2[128]
    float fe = NEGV, fo = NEGV, fx = NEGV;

    auto step = [&](float em_lv, float em_bv, int t) {
        float po = dpp_shr1(ao, NEGV);                    // old ao from lane-1
        float nae = la2(ae, po) + em_bv;                  // s = 2l
        float nao = (skip ? lse3(ao, ae, po)              // s = 2l+1
                          : la2(ao, ae)) + em_lv;
        float nax = la2(ax, ao) + em_bv;                  // s = 128 (lane 63)
        ae = nae; ao = nao; ax = nax;
        if (t == llm1) { fe = ae; fo = ao; fx = ax; }
    };

    auto consume = [&](int g) {              // 16 steps of group g
        const float (*rd)[66] = em[g & 1];
        float el[GR], eb[GR];
#pragma unroll
        for (int r = 0; r < GR; ++r) { el[r] = rd[r][lane]; eb[r] = rd[r][64]; }
        const int t0 = g * GR;
        if (g == 0) {
            // t=0 init: paths start at s=0 (blank) or s=1 (first label)
            ae = (lane == 0) ? eb[0] : NEGV;
            ao = (lane == 0) ? el[0] : NEGV;
            ax = NEGV;
            if (llm1 == 0) { fe = ae; fo = ao; fx = ax; }
#pragma unroll
            for (int r = 1; r < GR; ++r) step(el[r], eb[r], r);
        } else {
#pragma unroll
            for (int r = 0; r < GR; ++r) step(el[r], eb[r], t0 + r);
        }
    };

    // producer: emit one row into the ring
    auto emit_row = [&](int s, int row, const float4& x0, const float4& x1,
                        float xg) {
        float e = __expf(x0.x) + __expf(x0.y) + __expf(x0.z) + __expf(x0.w)
                + __expf(x1.x) + __expf(x1.y) + __expf(x1.z) + __expf(x1.w);
        float lse2 = __log2f(wave_sum_dpp(e));
        em[s][row][lane] = xg * INVLN2 - lse2;
        if (lane == 63)                      // x1.w = class 511 = blank
            em[s][row][64] = x1.w * INVLN2 - lse2;
    };

    for (int p = 0; p < NPH; ++p) {
        if (w < PW) {
            const int t = p * GR + w;
            float4 nA0, nA1, nB0, nB1; float ngA, ngB;
            if (p + 1 < NPH) {               // prefetch group p+1 (stays in
                const float4* qA =           // flight across the raw barrier)
                    (const float4*)(base + (size_t)(t + GR) * Cc);
                const float4* qB =
                    (const float4*)(base + (size_t)(t + GR + 8) * Cc);
                nA0 = qA[lane]; nA1 = qA[lane + 64];
                nB0 = qB[lane]; nB1 = qB[lane + 64];
                ngA = base[(size_t)(t + GR) * Cc + y];
                ngB = base[(size_t)(t + GR + 8) * Cc + y];
            }
            emit_row(p & 1, w,     cA0, cA1, cgA);
            emit_row(p & 1, w + 8, cB0, cB1, cgB);
            cA0 = nA0; cA1 = nA1; cgA = ngA;
            cB0 = nB0; cB1 = nB1; cgB = ngB;
        } else if (p > 0) {
            consume(p - 1);
        }
        phase_barrier();
    }

    // ---- tail: last group + nll extraction (wave 8) ----
    if (w == PW) {
        consume(NPH - 1);
        const int L  = lab_len[b];
        float f0 = (L == Lc) ? __shfl(fx, 63, 64) : __shfl(fe, L, 64);
        float f1 = __shfl(fo, L - 1, 64);
        if (lane == 0) nll[b] = -LN2 * la2(f0, f1);
    }
}

// Single block: mean of the 256 per-batch NLLs.
__global__ __launch_bounds__(256) void reduce_k(const float* __restrict__ nll,
                                                float* __restrict__ out) {
    int tid = threadIdx.x;
    float v = nll[tid];
#pragma unroll
    for (int o = 32; o; o >>= 1) v += __shfl_xor(v, o, 64);
    __shared__ float pr[4];
    if ((tid & 63) == 0) pr[tid >> 6] = v;
    __syncthreads();
    if (tid == 0) out[0] = (pr[0] + pr[1] + pr[2] + pr[3]) * (1.0f / Bc);
}

extern "C" void kernel_launch(void* const* d_in, const int* in_sizes, int n_in,
                              void* d_out, int out_size, void* d_ws, size_t ws_size,
                              hipStream_t stream) {
    const float* logits  = (const float*)d_in[0];
    const int*   labels  = (const int*)d_in[1];
    const int*   lab_len = (const int*)d_in[2];
    const int*   log_len = (const int*)d_in[3];
    float* out = (float*)d_out;
    float* nll = (float*)d_ws;                       // 256 floats

    hipLaunchKernelGGL(ctc_k, dim3(Bc), dim3(576), 0, stream,
                       logits, labels, lab_len, log_len, nll);
    hipLaunchKernelGGL(reduce_k, dim3(1), dim3(256), 0, stream, nll, out);
}